// Round 18
// baseline (91.658 us; speedup 1.0000x reference)
//
#include <hip/hip_runtime.h>
#include <hip/hip_bf16.h>

#define SEQ  256
#define DIM  20
#define NCLS 5
#define VROW 32                       // bf16 elems per table row (64 B)

typedef short  bf16x8 __attribute__((ext_vector_type(8)));
typedef float  f32x4  __attribute__((ext_vector_type(4)));
typedef float  v2f    __attribute__((ext_vector_type(2)));

__device__ __forceinline__ v2f fast_tanh2(v2f x) {
    // tanh(x) = 1 - 2/(exp(2x)+1); packed mul/add/fma, scalar exp/rcp
    v2f xs = x * 2.8853900817779268f;
    v2f e;
    e.x = __builtin_amdgcn_exp2f(xs.x);
    e.y = __builtin_amdgcn_exp2f(xs.y);
    v2f d = e + 1.0f;
    v2f r;
    r.x = __builtin_amdgcn_rcpf(d.x);
    r.y = __builtin_amdgcn_rcpf(d.y);
    return __builtin_elementwise_fma((v2f)(-2.0f), r, (v2f)(1.0f));
}

__device__ __forceinline__ int cvt_pk_bf16(float lo, float hi) {
    int r;
    asm("v_cvt_pk_bf16_f32 %0, %1, %2" : "=v"(r) : "v"(lo), "v"(hi));
    return r;
}

// v_permlane32_swap_b32 a, b  (S1 semantics, established by r8/r9 A-B result):
//   a' : lanes 0-31 = a(0-31),  lanes 32-63 = b(0-31)
//   b' : lanes 0-31 = a(32-63), lanes 32-63 = b(32-63)
__device__ __forceinline__ void pl32swap(int &a, int &b) {
    asm("v_permlane32_swap_b32 %0, %1" : "+v"(a), "+v"(b));
}

// Recurrent-contraction column permutation (A-column kappa holds unit
// perm(kappa)): [0-3]->u0-3, [4-7]->u8-11, [8-11]->u4-7, [12-15]->u12-15,
// [16-19]->u16-19. Whole h-exchange = 2 permlane32_swap, zero DS.
__device__ __forceinline__ int permk(int k) {
    return (k >= 4 && k < 8) ? k + 4 : (k >= 8 && k < 12) ? k - 4 : k;
}

union I4B { int i[4]; bf16x8 f; };

// ---- pre-pass: bf16 embedding table in B-fragment layout -------------------
// embB[tok][k], k<32: bf16(emb[tok][k]) for k<20 & tok!=0, else 0.
// Row 0 zeroed == padding_idx handled for free; RNE rounding == cvt_pk.
__global__ void build_embB(const float* __restrict__ emb,
                           unsigned short* __restrict__ embB, int V)
{
    int i = blockIdx.x * blockDim.x + threadIdx.x;
    const int N = V * VROW;
    const int stride = gridDim.x * blockDim.x;
    for (; i < N; i += stride) {
        const int tok = i >> 5, k = i & 31;
        float v = (k < DIM && tok != 0) ? emb[tok * DIM + k] : 0.0f;
        __hip_bfloat16 hb = __float2bfloat16(v);
        embB[i] = *reinterpret_cast<unsigned short*>(&hb);
    }
}

// ============================================================================
// Fast path: e-gather is ONE dwordx4 from the bf16 table straight into the
// B-fragment. Depth-2 token + depth-2 gather pipeline; scheduler occupancy
// pinned at 1 wave/EU (r17-proven: keeps the pipeline registers live).
// ============================================================================
__global__ __launch_bounds__(256)
__attribute__((amdgpu_waves_per_eu(1, 1)))
void rnn_mfma_tab(const int* __restrict__ x,
                  const unsigned short* __restrict__ embB,
                  const float* __restrict__ W_ih,
                  const float* __restrict__ W_hh,
                  const float* __restrict__ W_cls,
                  const float* __restrict__ b_cls,
                  float* __restrict__ out, int B)
{
    const int gtid = blockIdx.x * blockDim.x + threadIdx.x;
    const int wave = gtid >> 6;
    const int lane = (int)(threadIdx.x & 63);
    const int c = lane & 15;      // batch column of the tile
    const int q = lane >> 4;      // quadrant
    const int row0 = wave * 16;
    if (row0 >= B) return;

    // ---- A fragments: lane holds A[row=c][k=8q+j], zero outside bounds.
    auto loadA = [&](const float* M, int U0, int ROWS, bool pk) {
        bf16x8 f;
        const int uu = U0 + c;
        const int ur = uu < ROWS ? uu : 0;
#pragma unroll
        for (int j = 0; j < 8; ++j) {
            const int kk = 8 * q + j;
            const int kp = pk ? permk(kk) : kk;
            const int kr = kp < DIM ? kp : 0;
            float v = M[ur * DIM + kr];
            v = (uu < ROWS && kk < DIM) ? v : 0.0f;
            __hip_bfloat16 hb = __float2bfloat16(v);
            f[j] = *reinterpret_cast<short*>(&hb);
        }
        return f;
    };
    const bf16x8 A0h = loadA(W_hh,  0, DIM,  true);   // units 0-15,  W_hh
    const bf16x8 A0e = loadA(W_ih,  0, DIM,  false);  // units 0-15,  W_ih
    const bf16x8 A1h = loadA(W_hh, 16, DIM,  true);   // units 16-19
    const bf16x8 A1e = loadA(W_ih, 16, DIM,  false);
    const bf16x8 Acl = loadA(W_cls, 0, NCLS, true);   // classes 0-4

    float bias[4];
#pragma unroll
    for (int j = 0; j < 4; ++j) {
        const int idx = 4 * q + j;
        bias[j] = (idx < NCLS) ? b_cls[idx] : 0.0f;
    }

    const int* xp = x + (size_t)(row0 + c) * SEQ;
    const f32x4 zf = {0.0f, 0.0f, 0.0f, 0.0f};
    const unsigned short* ebq = embB + q * 8;    // quadrant's 16B slice

    // ---- prologue ----------------------------------------------------------
    I4B Bh; Bh.i[0] = Bh.i[1] = Bh.i[2] = Bh.i[3] = 0;
    const int tk0 = xp[0];
    const int tk1 = xp[1];
    const int tk2 = xp[2];
    I4B Be0;
    Be0.f = *(const bf16x8*)(ebq + (size_t)tk0 * VROW);
    f32x4 aePre0 = __builtin_amdgcn_mfma_f32_16x16x32_bf16(A0e, Be0.f, zf, 0, 0, 0);
    f32x4 aePre1 = __builtin_amdgcn_mfma_f32_16x16x32_bf16(A1e, Be0.f, zf, 0, 0, 0);

    // stage A = e(1), stage B = e(2); tokens: tokG = x[3], tokG2 = x[4]
    I4B gA, gB;
    gA.f = *(const bf16x8*)(ebq + (size_t)tk1 * VROW);
    gB.f = *(const bf16x8*)(ebq + (size_t)tk2 * VROW);
    int tokG  = xp[3];
    int tokG2 = xp[4];

    // ---- main loop ---------------------------------------------------------
#pragma unroll 4
    for (int s = 0; s < SEQ; ++s) {
        // issue: gather e(s+3) via tokG = x[s+3] (2-iter-old token),
        // and token x[s+5] (consumed 2 iterations from now)
        I4B gC;
        gC.f = *(const bf16x8*)(ebq + (size_t)tokG * VROW);
        const int i5 = (s + 5 < SEQ) ? (s + 5) : (SEQ - 1);
        const int tokNew = xp[i5];

        // h-MFMA chain (aePre is a ready C operand)
        const f32x4 acc0 = __builtin_amdgcn_mfma_f32_16x16x32_bf16(A0h, Bh.f, aePre0, 0, 0, 0);
        const f32x4 acc1 = __builtin_amdgcn_mfma_f32_16x16x32_bf16(A1h, Bh.f, aePre1, 0, 0, 0);

        const v2f p0 = fast_tanh2((v2f){acc0[0], acc0[1]});
        const v2f p1 = fast_tanh2((v2f){acc0[2], acc0[3]});
        const v2f p2 = fast_tanh2((v2f){acc1[0], acc1[1]});
        const v2f p3 = fast_tanh2((v2f){acc1[2], acc1[3]});
        int w0  = cvt_pk_bf16(p0.x, p0.y);
        int w1  = cvt_pk_bf16(p1.x, p1.y);
        int tp0 = cvt_pk_bf16(p2.x, p2.y);
        int tp1 = cvt_pk_bf16(p3.x, p3.y);
        pl32swap(w0, tp0);   // w' = {w_low, t_low}; t' = {w_high, t_high}
        pl32swap(w1, tp1);
        Bh.i[0] = w0;
        Bh.i[1] = w1;
        Bh.i[2] = tp0;
        Bh.i[3] = tp1;

        // e-MFMAs for step s+1 from stage A = e(s+1), loads 2 iters old
        aePre0 = __builtin_amdgcn_mfma_f32_16x16x32_bf16(A0e, gA.f, zf, 0, 0, 0);
        aePre1 = __builtin_amdgcn_mfma_f32_16x16x32_bf16(A1e, gA.f, zf, 0, 0, 0);

        // rotate pipeline stages (renamed by the unroll)
        gA = gB; gB = gC;
        tokG = tokG2; tokG2 = tokNew;
    }

    // ---- classifier: one MFMA (classes in rows 0-4; k-cols >= 20 are zero)
    const f32x4 y = __builtin_amdgcn_mfma_f32_16x16x32_bf16(Acl, Bh.f, zf, 0, 0, 0);
    float* orow = out + (size_t)(row0 + c) * NCLS;
    if (q == 0) {
        orow[0] = y[0] + bias[0];
        orow[1] = y[1] + bias[1];
        orow[2] = y[2] + bias[2];
        orow[3] = y[3] + bias[3];
    } else if (q == 1) {
        orow[4] = y[0] + bias[0];
    }
}

// ============================================================================
// Fallback (r17 verbatim, passing @74.7us): used when ws_size < table size.
// ============================================================================
__global__ __launch_bounds__(256)
__attribute__((amdgpu_waves_per_eu(1, 1)))
void rnn_mfma_fb(const int* __restrict__ x,
                 const float* __restrict__ emb,
                 const float* __restrict__ W_ih,
                 const float* __restrict__ W_hh,
                 const float* __restrict__ W_cls,
                 const float* __restrict__ b_cls,
                 float* __restrict__ out, int B)
{
    const int gtid = blockIdx.x * blockDim.x + threadIdx.x;
    const int wave = gtid >> 6;
    const int lane = (int)(threadIdx.x & 63);
    const int c = lane & 15;
    const int q = lane >> 4;
    const int row0 = wave * 16;
    if (row0 >= B) return;

    auto loadA = [&](const float* M, int U0, int ROWS, bool pk) {
        bf16x8 f;
        const int uu = U0 + c;
        const int ur = uu < ROWS ? uu : 0;
#pragma unroll
        for (int j = 0; j < 8; ++j) {
            const int kk = 8 * q + j;
            const int kp = pk ? permk(kk) : kk;
            const int kr = kp < DIM ? kp : 0;
            float v = M[ur * DIM + kr];
            v = (uu < ROWS && kk < DIM) ? v : 0.0f;
            __hip_bfloat16 hb = __float2bfloat16(v);
            f[j] = *reinterpret_cast<short*>(&hb);
        }
        return f;
    };
    const bf16x8 A0h = loadA(W_hh,  0, DIM,  true);
    const bf16x8 A0e = loadA(W_ih,  0, DIM,  false);
    const bf16x8 A1h = loadA(W_hh, 16, DIM,  true);
    const bf16x8 A1e = loadA(W_ih, 16, DIM,  false);
    const bf16x8 Acl = loadA(W_cls, 0, NCLS, true);

    float bias[4];
#pragma unroll
    for (int j = 0; j < 4; ++j) {
        const int idx = 4 * q + j;
        bias[j] = (idx < NCLS) ? b_cls[idx] : 0.0f;
    }

    const int eoff0 = (q == 0) ? 0 : (q == 1) ? 8 : 16;
    const int eoff1 = (q == 0) ? 4 : (q == 1) ? 12 : 16;

    const int* xp = x + (size_t)(row0 + c) * SEQ;
    const f32x4 zf = {0.0f, 0.0f, 0.0f, 0.0f};

    I4B Bh; Bh.i[0] = Bh.i[1] = Bh.i[2] = Bh.i[3] = 0;
    I4B Be;
    const int tk0 = xp[0];
    const int tk1 = xp[1];
    const int tk2 = xp[2];
    {
        const f32x4 lo = *(const f32x4*)(emb + (size_t)tk0 * DIM + eoff0);
        const f32x4 hi = *(const f32x4*)(emb + (size_t)tk0 * DIM + eoff1);
        const bool nz = (tk0 != 0);
        Be.i[0] = nz ? cvt_pk_bf16(lo[0], lo[1]) : 0;
        Be.i[1] = nz ? cvt_pk_bf16(lo[2], lo[3]) : 0;
        Be.i[2] = nz ? cvt_pk_bf16(hi[0], hi[1]) : 0;
        Be.i[3] = nz ? cvt_pk_bf16(hi[2], hi[3]) : 0;
    }
    f32x4 aePre0 = __builtin_amdgcn_mfma_f32_16x16x32_bf16(A0e, Be.f, zf, 0, 0, 0);
    f32x4 aePre1 = __builtin_amdgcn_mfma_f32_16x16x32_bf16(A1e, Be.f, zf, 0, 0, 0);

    f32x4 loA, hiA, loB, hiB;
    bool nzA, nzB;
    loA = *(const f32x4*)(emb + (size_t)tk1 * DIM + eoff0);
    hiA = *(const f32x4*)(emb + (size_t)tk1 * DIM + eoff1);
    nzA = (tk1 != 0);
    loB = *(const f32x4*)(emb + (size_t)tk2 * DIM + eoff0);
    hiB = *(const f32x4*)(emb + (size_t)tk2 * DIM + eoff1);
    nzB = (tk2 != 0);
    int tokG  = xp[3];
    int tokG2 = xp[4];

#pragma unroll 4
    for (int s = 0; s < SEQ; ++s) {
        const f32x4 loC = *(const f32x4*)(emb + (size_t)tokG * DIM + eoff0);
        const f32x4 hiC = *(const f32x4*)(emb + (size_t)tokG * DIM + eoff1);
        const bool nzC = (tokG != 0);
        const int i5 = (s + 5 < SEQ) ? (s + 5) : (SEQ - 1);
        const int tokNew = xp[i5];

        const f32x4 acc0 = __builtin_amdgcn_mfma_f32_16x16x32_bf16(A0h, Bh.f, aePre0, 0, 0, 0);
        const f32x4 acc1 = __builtin_amdgcn_mfma_f32_16x16x32_bf16(A1h, Bh.f, aePre1, 0, 0, 0);

        const v2f p0 = fast_tanh2((v2f){acc0[0], acc0[1]});
        const v2f p1 = fast_tanh2((v2f){acc0[2], acc0[3]});
        const v2f p2 = fast_tanh2((v2f){acc1[0], acc1[1]});
        const v2f p3 = fast_tanh2((v2f){acc1[2], acc1[3]});
        int w0  = cvt_pk_bf16(p0.x, p0.y);
        int w1  = cvt_pk_bf16(p1.x, p1.y);
        int tp0 = cvt_pk_bf16(p2.x, p2.y);
        int tp1 = cvt_pk_bf16(p3.x, p3.y);
        pl32swap(w0, tp0);
        pl32swap(w1, tp1);
        Bh.i[0] = w0;
        Bh.i[1] = w1;
        Bh.i[2] = tp0;
        Bh.i[3] = tp1;

        Be.i[0] = nzA ? cvt_pk_bf16(loA[0], loA[1]) : 0;
        Be.i[1] = nzA ? cvt_pk_bf16(loA[2], loA[3]) : 0;
        Be.i[2] = nzA ? cvt_pk_bf16(hiA[0], hiA[1]) : 0;
        Be.i[3] = nzA ? cvt_pk_bf16(hiA[2], hiA[3]) : 0;

        aePre0 = __builtin_amdgcn_mfma_f32_16x16x32_bf16(A0e, Be.f, zf, 0, 0, 0);
        aePre1 = __builtin_amdgcn_mfma_f32_16x16x32_bf16(A1e, Be.f, zf, 0, 0, 0);

        loA = loB; hiA = hiB; nzA = nzB;
        loB = loC; hiB = hiC; nzB = nzC;
        tokG = tokG2; tokG2 = tokNew;
    }

    const f32x4 y = __builtin_amdgcn_mfma_f32_16x16x32_bf16(Acl, Bh.f, zf, 0, 0, 0);
    float* orow = out + (size_t)(row0 + c) * NCLS;
    if (q == 0) {
        orow[0] = y[0] + bias[0];
        orow[1] = y[1] + bias[1];
        orow[2] = y[2] + bias[2];
        orow[3] = y[3] + bias[3];
    } else if (q == 1) {
        orow[4] = y[0] + bias[0];
    }
}

extern "C" void kernel_launch(void* const* d_in, const int* in_sizes, int n_in,
                              void* d_out, int out_size, void* d_ws, size_t ws_size,
                              hipStream_t stream) {
    const int*   x     = (const int*)d_in[0];
    const float* emb   = (const float*)d_in[1];
    const float* W_ih  = (const float*)d_in[2];
    const float* W_hh  = (const float*)d_in[3];
    const float* W_cls = (const float*)d_in[4];
    const float* b_cls = (const float*)d_in[5];
    float* out = (float*)d_out;

    const int B = in_sizes[0] / SEQ;            // 16384
    const int V = in_sizes[1] / DIM;            // 50000
    const size_t tabBytes = (size_t)V * VROW * sizeof(unsigned short);  // 3.2 MB

    const int threads = B * 4;                   // 64 lanes per 16 rows
    const int block = 256;
    const int grid = (threads + block - 1) / block;   // 1024 waves total

    if (d_ws != nullptr && ws_size >= tabBytes) {
        unsigned short* embB = (unsigned short*)d_ws;
        build_embB<<<1024, 256, 0, stream>>>(emb, embB, V);
        rnn_mfma_tab<<<grid, block, 0, stream>>>(x, embB, W_ih, W_hh, W_cls, b_cls, out, B);
    } else {
        rnn_mfma_fb<<<grid, block, 0, stream>>>(x, emb, W_ih, W_hh, W_cls, b_cls, out, B);
    }
}

// Round 19
// 73.412 us; speedup vs baseline: 1.2485x; 1.2485x over previous
//
#include <hip/hip_runtime.h>
#include <hip/hip_bf16.h>

#define SEQ  256
#define DIM  20
#define NCLS 5

typedef short  bf16x8 __attribute__((ext_vector_type(8)));
typedef float  f32x4  __attribute__((ext_vector_type(4)));
typedef float  v2f    __attribute__((ext_vector_type(2)));

__device__ __forceinline__ v2f fast_tanh2(v2f x) {
    // tanh(x) = 1 - 2/(exp(2x)+1); packed mul/add/fma, scalar exp/rcp
    v2f xs = x * 2.8853900817779268f;
    v2f e;
    e.x = __builtin_amdgcn_exp2f(xs.x);
    e.y = __builtin_amdgcn_exp2f(xs.y);
    v2f d = e + 1.0f;
    v2f r;
    r.x = __builtin_amdgcn_rcpf(d.x);
    r.y = __builtin_amdgcn_rcpf(d.y);
    return __builtin_elementwise_fma((v2f)(-2.0f), r, (v2f)(1.0f));
}

__device__ __forceinline__ int cvt_pk_bf16(float lo, float hi) {
    int r;
    asm("v_cvt_pk_bf16_f32 %0, %1, %2" : "=v"(r) : "v"(lo), "v"(hi));
    return r;
}

// v_permlane32_swap_b32 a, b  (S1 semantics, established by r8/r9 A-B result):
//   a' : lanes 0-31 = a(0-31),  lanes 32-63 = b(0-31)
//   b' : lanes 0-31 = a(32-63), lanes 32-63 = b(32-63)
__device__ __forceinline__ void pl32swap(int &a, int &b) {
    asm("v_permlane32_swap_b32 %0, %1" : "+v"(a), "+v"(b));
}

// Recurrent-contraction column permutation (A-column kappa holds unit
// perm(kappa)): [0-3]->u0-3, [4-7]->u8-11, [8-11]->u4-7, [12-15]->u12-15,
// [16-19]->u16-19. Whole h-exchange = 2 permlane32_swap, zero DS.
__device__ __forceinline__ int permk(int k) {
    return (k >= 4 && k < 8) ? k + 4 : (k >= 8 && k < 12) ? k - 4 : k;
}

union I4B { int i[4]; bf16x8 f; };

// One RNN step. TIDX: index of the token to load this iteration (x[s+9]).
// Depth-4 stages (A..D) + 4 tokens in flight; under #pragma unroll 4 the
// 4-stage rotation renames exactly (zero v_mov), and every load has ~4
// iterations (~3000 cyc) of cover.
#define STEP(TIDX)                                                             \
    {                                                                          \
        /* issue gather e(s+5) via tokG0 = x[s+5] (4-iter-old token) */        \
        const f32x4 loN = *(const f32x4*)(emb + (size_t)tokG0 * DIM + eoff0);  \
        const f32x4 hiN = *(const f32x4*)(emb + (size_t)tokG0 * DIM + eoff1);  \
        const bool  nzN = (tokG0 != 0);                                        \
        const int tokNew = xp[(TIDX)];                                         \
        /* h-MFMA chain (aePre is a ready C operand) */                        \
        const f32x4 acc0 = __builtin_amdgcn_mfma_f32_16x16x32_bf16(A0h, Bh.f, aePre0, 0, 0, 0); \
        const f32x4 acc1 = __builtin_amdgcn_mfma_f32_16x16x32_bf16(A1h, Bh.f, aePre1, 0, 0, 0); \
        const v2f p0 = fast_tanh2((v2f){acc0[0], acc0[1]});                    \
        const v2f p1 = fast_tanh2((v2f){acc0[2], acc0[3]});                    \
        const v2f p2 = fast_tanh2((v2f){acc1[0], acc1[1]});                    \
        const v2f p3 = fast_tanh2((v2f){acc1[2], acc1[3]});                    \
        int w0  = cvt_pk_bf16(p0.x, p0.y);                                     \
        int w1  = cvt_pk_bf16(p1.x, p1.y);                                     \
        int tp0 = cvt_pk_bf16(p2.x, p2.y);                                     \
        int tp1 = cvt_pk_bf16(p3.x, p3.y);                                     \
        pl32swap(w0, tp0);   /* w'={w_lo,t_lo}; t'={w_hi,t_hi} */              \
        pl32swap(w1, tp1);                                                     \
        Bh.i[0] = w0; Bh.i[1] = w1; Bh.i[2] = tp0; Bh.i[3] = tp1;              \
        /* consume stage A = e(s+1): loads 4 iterations old */                 \
        I4B Be;                                                                \
        Be.i[0] = nzA ? cvt_pk_bf16(loA[0], loA[1]) : 0;                       \
        Be.i[1] = nzA ? cvt_pk_bf16(loA[2], loA[3]) : 0;                       \
        Be.i[2] = nzA ? cvt_pk_bf16(hiA[0], hiA[1]) : 0;                       \
        Be.i[3] = nzA ? cvt_pk_bf16(hiA[2], hiA[3]) : 0;                       \
        aePre0 = __builtin_amdgcn_mfma_f32_16x16x32_bf16(A0e, Be.f, zf, 0, 0, 0); \
        aePre1 = __builtin_amdgcn_mfma_f32_16x16x32_bf16(A1e, Be.f, zf, 0, 0, 0); \
        /* rotate: renamed away exactly by unroll 4 */                         \
        loA = loB; hiA = hiB; nzA = nzB;                                       \
        loB = loC; hiB = hiC; nzB = nzC;                                       \
        loC = loD; hiC = hiD; nzC = nzD;                                       \
        loD = loN; hiD = hiN; nzD = nzN;                                       \
        tokG0 = tokG1; tokG1 = tokG2; tokG2 = tokG3; tokG3 = tokNew;           \
    }

// One wave = 16 batch rows; plain loads; scheduler occupancy pinned to
// 1 wave/EU (r17-proven: keeps pipeline registers live, VGPR 48->132).
__global__ __launch_bounds__(256)
__attribute__((amdgpu_waves_per_eu(1, 1)))
void rnn_mfma(const int* __restrict__ x,
              const float* __restrict__ emb,
              const float* __restrict__ W_ih,
              const float* __restrict__ W_hh,
              const float* __restrict__ W_cls,
              const float* __restrict__ b_cls,
              float* __restrict__ out, int B)
{
    const int gtid = blockIdx.x * blockDim.x + threadIdx.x;
    const int wave = gtid >> 6;
    const int lane = (int)(threadIdx.x & 63);
    const int c = lane & 15;      // batch column of the tile
    const int q = lane >> 4;      // quadrant
    const int row0 = wave * 16;
    if (row0 >= B) return;

    // ---- A fragments: lane holds A[row=c][k=8q+j], zero outside bounds.
    auto loadA = [&](const float* M, int U0, int ROWS, bool pk) {
        bf16x8 f;
        const int uu = U0 + c;
        const int ur = uu < ROWS ? uu : 0;
#pragma unroll
        for (int j = 0; j < 8; ++j) {
            const int kk = 8 * q + j;
            const int kp = pk ? permk(kk) : kk;
            const int kr = kp < DIM ? kp : 0;
            float v = M[ur * DIM + kr];
            v = (uu < ROWS && kk < DIM) ? v : 0.0f;
            __hip_bfloat16 hb = __float2bfloat16(v);
            f[j] = *reinterpret_cast<short*>(&hb);
        }
        return f;
    };
    const bf16x8 A0h = loadA(W_hh,  0, DIM,  true);   // units 0-15,  W_hh
    const bf16x8 A0e = loadA(W_ih,  0, DIM,  false);  // units 0-15,  W_ih
    const bf16x8 A1h = loadA(W_hh, 16, DIM,  true);   // units 16-19
    const bf16x8 A1e = loadA(W_ih, 16, DIM,  false);
    const bf16x8 Acl = loadA(W_cls, 0, NCLS, true);   // classes 0-4

    float bias[4];
#pragma unroll
    for (int j = 0; j < 4; ++j) {
        const int idx = 4 * q + j;
        bias[j] = (idx < NCLS) ? b_cls[idx] : 0.0f;
    }

    const int eoff0 = (q == 0) ? 0 : (q == 1) ? 8 : 16;   // e element offsets,
    const int eoff1 = (q == 0) ? 4 : (q == 1) ? 12 : 16;  // clamped in-bounds

    const int* xp = x + (size_t)(row0 + c) * SEQ;
    const f32x4 zf = {0.0f, 0.0f, 0.0f, 0.0f};

    // ---- prologue ----------------------------------------------------------
    I4B Bh; Bh.i[0] = Bh.i[1] = Bh.i[2] = Bh.i[3] = 0;
    const int tk0 = xp[0];
    const int tk1 = xp[1];
    const int tk2 = xp[2];
    const int tk3 = xp[3];
    const int tk4 = xp[4];
    f32x4 aePre0, aePre1;
    {   // e(0) -> aePre for step 0
        const f32x4 lo = *(const f32x4*)(emb + (size_t)tk0 * DIM + eoff0);
        const f32x4 hi = *(const f32x4*)(emb + (size_t)tk0 * DIM + eoff1);
        const bool nz = (tk0 != 0);    // padding_idx = 0
        I4B Be;
        Be.i[0] = nz ? cvt_pk_bf16(lo[0], lo[1]) : 0;
        Be.i[1] = nz ? cvt_pk_bf16(lo[2], lo[3]) : 0;
        Be.i[2] = nz ? cvt_pk_bf16(hi[0], hi[1]) : 0;
        Be.i[3] = nz ? cvt_pk_bf16(hi[2], hi[3]) : 0;
        aePre0 = __builtin_amdgcn_mfma_f32_16x16x32_bf16(A0e, Be.f, zf, 0, 0, 0);
        aePre1 = __builtin_amdgcn_mfma_f32_16x16x32_bf16(A1e, Be.f, zf, 0, 0, 0);
    }

    // stages A..D = e(1)..e(4); tokens x[5..8] in flight
    f32x4 loA, hiA, loB, hiB, loC, hiC, loD, hiD;
    bool nzA, nzB, nzC, nzD;
    loA = *(const f32x4*)(emb + (size_t)tk1 * DIM + eoff0);
    hiA = *(const f32x4*)(emb + (size_t)tk1 * DIM + eoff1);
    nzA = (tk1 != 0);
    loB = *(const f32x4*)(emb + (size_t)tk2 * DIM + eoff0);
    hiB = *(const f32x4*)(emb + (size_t)tk2 * DIM + eoff1);
    nzB = (tk2 != 0);
    loC = *(const f32x4*)(emb + (size_t)tk3 * DIM + eoff0);
    hiC = *(const f32x4*)(emb + (size_t)tk3 * DIM + eoff1);
    nzC = (tk3 != 0);
    loD = *(const f32x4*)(emb + (size_t)tk4 * DIM + eoff0);
    hiD = *(const f32x4*)(emb + (size_t)tk4 * DIM + eoff1);
    nzD = (tk4 != 0);
    int tokG0 = xp[5];
    int tokG1 = xp[6];
    int tokG2 = xp[7];
    int tokG3 = xp[8];

    // ---- main loop: no clamp needed while s+9 <= 255 (s < 244, 4-aligned) --
#pragma unroll 4
    for (int s = 0; s < 244; ++s) {
        STEP(s + 9)
    }
    // ---- tail: 12 steps with clamped token index ---------------------------
#pragma unroll 4
    for (int s = 244; s < SEQ; ++s) {
        STEP((s + 9 < SEQ) ? (s + 9) : (SEQ - 1))
    }

    // ---- classifier: one MFMA (classes in rows 0-4; k-cols >= 20 are zero)
    const f32x4 y = __builtin_amdgcn_mfma_f32_16x16x32_bf16(Acl, Bh.f, zf, 0, 0, 0);
    float* orow = out + (size_t)(row0 + c) * NCLS;
    if (q == 0) {          // rows 0-3 = classes 0-3 for batch row c
        orow[0] = y[0] + bias[0];
        orow[1] = y[1] + bias[1];
        orow[2] = y[2] + bias[2];
        orow[3] = y[3] + bias[3];
    } else if (q == 1) {   // row 4 = class 4
        orow[4] = y[0] + bias[0];
    }
}

extern "C" void kernel_launch(void* const* d_in, const int* in_sizes, int n_in,
                              void* d_out, int out_size, void* d_ws, size_t ws_size,
                              hipStream_t stream) {
    const int*   x     = (const int*)d_in[0];
    const float* emb   = (const float*)d_in[1];
    const float* W_ih  = (const float*)d_in[2];
    const float* W_hh  = (const float*)d_in[3];
    const float* W_cls = (const float*)d_in[4];
    const float* b_cls = (const float*)d_in[5];
    float* out = (float*)d_out;

    const int B = in_sizes[0] / SEQ;            // 16384
    const int threads = B * 4;                   // 64 lanes per 16 rows
    const int block = 256;
    const int grid = (threads + block - 1) / block;   // 1024 waves total
    rnn_mfma<<<grid, block, 0, stream>>>(x, emb, W_ih, W_hh, W_cls, b_cls, out, B);
}

// Round 20
// 68.651 us; speedup vs baseline: 1.3351x; 1.0693x over previous
//
#include <hip/hip_runtime.h>
#include <hip/hip_bf16.h>

#define SEQ  256
#define DIM  20
#define NCLS 5

typedef short  bf16x8 __attribute__((ext_vector_type(8)));
typedef float  f32x4  __attribute__((ext_vector_type(4)));
typedef float  v2f    __attribute__((ext_vector_type(2)));

__device__ __forceinline__ v2f fast_tanh2(v2f x) {
    // tanh(x) = 1 - 2/(exp(2x)+1); packed mul/add/fma, scalar exp/rcp
    v2f xs = x * 2.8853900817779268f;
    v2f e;
    e.x = __builtin_amdgcn_exp2f(xs.x);
    e.y = __builtin_amdgcn_exp2f(xs.y);
    v2f d = e + 1.0f;
    v2f r;
    r.x = __builtin_amdgcn_rcpf(d.x);
    r.y = __builtin_amdgcn_rcpf(d.y);
    return __builtin_elementwise_fma((v2f)(-2.0f), r, (v2f)(1.0f));
}

__device__ __forceinline__ int cvt_pk_bf16(float lo, float hi) {
    int r;
    asm("v_cvt_pk_bf16_f32 %0, %1, %2" : "=v"(r) : "v"(lo), "v"(hi));
    return r;
}

// v_permlane32_swap_b32 a, b  (S1 semantics, established by r8/r9 A-B result):
//   a' : lanes 0-31 = a(0-31),  lanes 32-63 = b(0-31)
//   b' : lanes 0-31 = a(32-63), lanes 32-63 = b(32-63)
__device__ __forceinline__ void pl32swap(int &a, int &b) {
    asm("v_permlane32_swap_b32 %0, %1" : "+v"(a), "+v"(b));
}

// Recurrent-contraction column permutation (A-column kappa holds unit
// perm(kappa)): [0-3]->u0-3, [4-7]->u8-11, [8-11]->u4-7, [12-15]->u12-15,
// [16-19]->u16-19. Whole h-exchange = 2 permlane32_swap, zero DS.
__device__ __forceinline__ int permk(int k) {
    return (k >= 4 && k < 8) ? k + 4 : (k >= 8 && k < 12) ? k - 4 : k;
}

union I4B { int i[4]; bf16x8 f; };

// One RNN step, REORDERED so the independent e-path (Be convert + e-MFMA,
// inputs are 4-iteration-old loads) issues INSIDE the h-MFMA latency shadow,
// and tanh reads acc only after ~14 intervening instructions. Arithmetic is
// identical to r19 (same ops, same operands) — only instruction order moved.
#define STEP(TIDX)                                                            \
    {                                                                          \
        /* 1. issue gather e(s+5) via tokG0 = x[s+5] (4-iter-old token) */     \
        const f32x4 loN = *(const f32x4*)(emb + (size_t)tokG0 * DIM + eoff0);  \
        const f32x4 hiN = *(const f32x4*)(emb + (size_t)tokG0 * DIM + eoff1);  \
        const bool  nzN = (tokG0 != 0);                                        \
        const int tokNew = xp[(TIDX)];                                         \
        /* 2. h-MFMA issue (aePre ready since mid-previous-step) */            \
        const f32x4 acc0 = __builtin_amdgcn_mfma_f32_16x16x32_bf16(A0h, Bh.f, aePre0, 0, 0, 0); \
        const f32x4 acc1 = __builtin_amdgcn_mfma_f32_16x16x32_bf16(A1h, Bh.f, aePre1, 0, 0, 0); \
        /* 3. e-path fills the h-MFMA latency shadow (independent of acc) */   \
        I4B Be;                                                                \
        Be.i[0] = nzA ? cvt_pk_bf16(loA[0], loA[1]) : 0;                       \
        Be.i[1] = nzA ? cvt_pk_bf16(loA[2], loA[3]) : 0;                       \
        Be.i[2] = nzA ? cvt_pk_bf16(hiA[0], hiA[1]) : 0;                       \
        Be.i[3] = nzA ? cvt_pk_bf16(hiA[2], hiA[3]) : 0;                       \
        aePre0 = __builtin_amdgcn_mfma_f32_16x16x32_bf16(A0e, Be.f, zf, 0, 0, 0); \
        aePre1 = __builtin_amdgcn_mfma_f32_16x16x32_bf16(A1e, Be.f, zf, 0, 0, 0); \
        /* 4. tanh: acc latency has elapsed under step 3 */                    \
        const v2f p0 = fast_tanh2((v2f){acc0[0], acc0[1]});                    \
        const v2f p1 = fast_tanh2((v2f){acc0[2], acc0[3]});                    \
        const v2f p2 = fast_tanh2((v2f){acc1[0], acc1[1]});                    \
        const v2f p3 = fast_tanh2((v2f){acc1[2], acc1[3]});                    \
        int w0  = cvt_pk_bf16(p0.x, p0.y);                                     \
        int w1  = cvt_pk_bf16(p1.x, p1.y);                                     \
        int tp0 = cvt_pk_bf16(p2.x, p2.y);                                     \
        int tp1 = cvt_pk_bf16(p3.x, p3.y);                                     \
        pl32swap(w0, tp0);   /* w'={w_lo,t_lo}; t'={w_hi,t_hi} */              \
        pl32swap(w1, tp1);                                                     \
        Bh.i[0] = w0; Bh.i[1] = w1; Bh.i[2] = tp0; Bh.i[3] = tp1;              \
        /* 5. rotate: renamed away exactly by the unroll (multiple of 4) */    \
        loA = loB; hiA = hiB; nzA = nzB;                                       \
        loB = loC; hiB = hiC; nzB = nzC;                                       \
        loC = loD; hiC = hiD; nzC = nzD;                                       \
        loD = loN; hiD = hiN; nzD = nzN;                                       \
        tokG0 = tokG1; tokG1 = tokG2; tokG2 = tokG3; tokG3 = tokNew;           \
    }

// One wave = 16 batch rows; plain loads; scheduler occupancy pinned to
// 1 wave/EU (r17-proven: keeps pipeline registers live, VGPR 48->132).
__global__ __launch_bounds__(256)
__attribute__((amdgpu_waves_per_eu(1, 1)))
void rnn_mfma(const int* __restrict__ x,
              const float* __restrict__ emb,
              const float* __restrict__ W_ih,
              const float* __restrict__ W_hh,
              const float* __restrict__ W_cls,
              const float* __restrict__ b_cls,
              float* __restrict__ out, int B)
{
    const int gtid = blockIdx.x * blockDim.x + threadIdx.x;
    const int wave = gtid >> 6;
    const int lane = (int)(threadIdx.x & 63);
    const int c = lane & 15;      // batch column of the tile
    const int q = lane >> 4;      // quadrant
    const int row0 = wave * 16;
    if (row0 >= B) return;

    // ---- A fragments: lane holds A[row=c][k=8q+j], zero outside bounds.
    auto loadA = [&](const float* M, int U0, int ROWS, bool pk) {
        bf16x8 f;
        const int uu = U0 + c;
        const int ur = uu < ROWS ? uu : 0;
#pragma unroll
        for (int j = 0; j < 8; ++j) {
            const int kk = 8 * q + j;
            const int kp = pk ? permk(kk) : kk;
            const int kr = kp < DIM ? kp : 0;
            float v = M[ur * DIM + kr];
            v = (uu < ROWS && kk < DIM) ? v : 0.0f;
            __hip_bfloat16 hb = __float2bfloat16(v);
            f[j] = *reinterpret_cast<short*>(&hb);
        }
        return f;
    };
    const bf16x8 A0h = loadA(W_hh,  0, DIM,  true);   // units 0-15,  W_hh
    const bf16x8 A0e = loadA(W_ih,  0, DIM,  false);  // units 0-15,  W_ih
    const bf16x8 A1h = loadA(W_hh, 16, DIM,  true);   // units 16-19
    const bf16x8 A1e = loadA(W_ih, 16, DIM,  false);
    const bf16x8 Acl = loadA(W_cls, 0, NCLS, true);   // classes 0-4

    float bias[4];
#pragma unroll
    for (int j = 0; j < 4; ++j) {
        const int idx = 4 * q + j;
        bias[j] = (idx < NCLS) ? b_cls[idx] : 0.0f;
    }

    const int eoff0 = (q == 0) ? 0 : (q == 1) ? 8 : 16;   // e element offsets,
    const int eoff1 = (q == 0) ? 4 : (q == 1) ? 12 : 16;  // clamped in-bounds

    const int* xp = x + (size_t)(row0 + c) * SEQ;
    const f32x4 zf = {0.0f, 0.0f, 0.0f, 0.0f};

    // ---- prologue ----------------------------------------------------------
    I4B Bh; Bh.i[0] = Bh.i[1] = Bh.i[2] = Bh.i[3] = 0;
    const int tk0 = xp[0];
    const int tk1 = xp[1];
    const int tk2 = xp[2];
    const int tk3 = xp[3];
    const int tk4 = xp[4];
    f32x4 aePre0, aePre1;
    {   // e(0) -> aePre for step 0
        const f32x4 lo = *(const f32x4*)(emb + (size_t)tk0 * DIM + eoff0);
        const f32x4 hi = *(const f32x4*)(emb + (size_t)tk0 * DIM + eoff1);
        const bool nz = (tk0 != 0);    // padding_idx = 0
        I4B Be;
        Be.i[0] = nz ? cvt_pk_bf16(lo[0], lo[1]) : 0;
        Be.i[1] = nz ? cvt_pk_bf16(lo[2], lo[3]) : 0;
        Be.i[2] = nz ? cvt_pk_bf16(hi[0], hi[1]) : 0;
        Be.i[3] = nz ? cvt_pk_bf16(hi[2], hi[3]) : 0;
        aePre0 = __builtin_amdgcn_mfma_f32_16x16x32_bf16(A0e, Be.f, zf, 0, 0, 0);
        aePre1 = __builtin_amdgcn_mfma_f32_16x16x32_bf16(A1e, Be.f, zf, 0, 0, 0);
    }

    // stages A..D = e(1)..e(4); tokens x[5..8] in flight
    f32x4 loA, hiA, loB, hiB, loC, hiC, loD, hiD;
    bool nzA, nzB, nzC, nzD;
    loA = *(const f32x4*)(emb + (size_t)tk1 * DIM + eoff0);
    hiA = *(const f32x4*)(emb + (size_t)tk1 * DIM + eoff1);
    nzA = (tk1 != 0);
    loB = *(const f32x4*)(emb + (size_t)tk2 * DIM + eoff0);
    hiB = *(const f32x4*)(emb + (size_t)tk2 * DIM + eoff1);
    nzB = (tk2 != 0);
    loC = *(const f32x4*)(emb + (size_t)tk3 * DIM + eoff0);
    hiC = *(const f32x4*)(emb + (size_t)tk3 * DIM + eoff1);
    nzC = (tk3 != 0);
    loD = *(const f32x4*)(emb + (size_t)tk4 * DIM + eoff0);
    hiD = *(const f32x4*)(emb + (size_t)tk4 * DIM + eoff1);
    nzD = (tk4 != 0);
    int tokG0 = xp[5];
    int tokG1 = xp[6];
    int tokG2 = xp[7];
    int tokG3 = xp[8];

    // ---- main loop: no clamp needed while s+9 <= 255; 240 is 8-aligned -----
#pragma unroll 8
    for (int s = 0; s < 240; ++s) {
        STEP(s + 9)
    }
    // ---- tail: 16 steps with clamped token index ---------------------------
#pragma unroll 4
    for (int s = 240; s < SEQ; ++s) {
        STEP((s + 9 < SEQ) ? (s + 9) : (SEQ - 1))
    }

    // ---- classifier: one MFMA (classes in rows 0-4; k-cols >= 20 are zero)
    const f32x4 y = __builtin_amdgcn_mfma_f32_16x16x32_bf16(Acl, Bh.f, zf, 0, 0, 0);
    float* orow = out + (size_t)(row0 + c) * NCLS;
    if (q == 0) {          // rows 0-3 = classes 0-3 for batch row c
        orow[0] = y[0] + bias[0];
        orow[1] = y[1] + bias[1];
        orow[2] = y[2] + bias[2];
        orow[3] = y[3] + bias[3];
    } else if (q == 1) {   // row 4 = class 4
        orow[4] = y[0] + bias[0];
    }
}

extern "C" void kernel_launch(void* const* d_in, const int* in_sizes, int n_in,
                              void* d_out, int out_size, void* d_ws, size_t ws_size,
                              hipStream_t stream) {
    const int*   x     = (const int*)d_in[0];
    const float* emb   = (const float*)d_in[1];
    const float* W_ih  = (const float*)d_in[2];
    const float* W_hh  = (const float*)d_in[3];
    const float* W_cls = (const float*)d_in[4];
    const float* b_cls = (const float*)d_in[5];
    float* out = (float*)d_out;

    const int B = in_sizes[0] / SEQ;            // 16384
    const int threads = B * 4;                   // 64 lanes per 16 rows
    const int block = 256;
    const int grid = (threads + block - 1) / block;   // 1024 waves total
    rnn_mfma<<<grid, block, 0, stream>>>(x, emb, W_ih, W_hh, W_cls, b_cls, out, B);
}

// Round 21
// 68.594 us; speedup vs baseline: 1.3363x; 1.0008x over previous
//
#include <hip/hip_runtime.h>
#include <hip/hip_bf16.h>

#define SEQ  256
#define DIM  20
#define NCLS 5
#define ALPHA 2.8853900817779268f   // 2*log2(e): folded into recurrent weights

typedef short  bf16x8 __attribute__((ext_vector_type(8)));
typedef float  f32x4  __attribute__((ext_vector_type(4)));
typedef float  v2f    __attribute__((ext_vector_type(2)));

// tanh from PRE-SCALED input (xs = 2*log2e * pre): 1 - 2/(exp2(xs)+1).
// Paired reciprocal: one v_rcp serves both lanes of the pair (product of the
// two denominators; d >= 1 so prod in [1, ~1e9] -- no overflow, rel err ~1e-7).
__device__ __forceinline__ v2f fast_tanh2_s(v2f xs) {
    v2f e;
    e.x = __builtin_amdgcn_exp2f(xs.x);
    e.y = __builtin_amdgcn_exp2f(xs.y);
    v2f d = e + 1.0f;                     // v_pk_add_f32
    const float r = __builtin_amdgcn_rcpf(d.x * d.y);
    v2f inv;
    inv.x = d.y * r;
    inv.y = d.x * r;
    return __builtin_elementwise_fma((v2f)(-2.0f), inv, (v2f)(1.0f));
}

__device__ __forceinline__ int cvt_pk_bf16(float lo, float hi) {
    int r;
    asm("v_cvt_pk_bf16_f32 %0, %1, %2" : "=v"(r) : "v"(lo), "v"(hi));
    return r;
}

// v_permlane32_swap_b32 a, b  (S1 semantics, established by r8/r9 A-B result):
//   a' : lanes 0-31 = a(0-31),  lanes 32-63 = b(0-31)
//   b' : lanes 0-31 = a(32-63), lanes 32-63 = b(32-63)
__device__ __forceinline__ void pl32swap(int &a, int &b) {
    asm("v_permlane32_swap_b32 %0, %1" : "+v"(a), "+v"(b));
}

// Recurrent-contraction column permutation (A-column kappa holds unit
// perm(kappa)): [0-3]->u0-3, [4-7]->u8-11, [8-11]->u4-7, [12-15]->u12-15,
// [16-19]->u16-19. Whole h-exchange = 2 permlane32_swap, zero DS.
__device__ __forceinline__ int permk(int k) {
    return (k >= 4 && k < 8) ? k + 4 : (k >= 8 && k < 12) ? k - 4 : k;
}

union I4B { int i[4]; bf16x8 f; };

// One RNN step. Ordering tuned for the in-order single-wave pipeline:
//   1. gather + token issue (VMEM, covered 4 iterations ahead)
//   2. h-MFMA tile1 then tile0 (acc1 result arrives first)
//   3. e-path (independent) fills the MFMA latency shadow
//   4. tanh tile1 -> pack t's (acc0 latency hides under tile1 trans work)
//   5. tanh tile0 -> pack w's -> 2 permlane swaps -> Bh
// Weights pre-scaled by ALPHA: acc is already in exp2 units (no pk_mul).
#define STEP(TIDX)                                                            \
    {                                                                          \
        const f32x4 loN = *(const f32x4*)(emb + (size_t)tokG0 * DIM + eoff0);  \
        const f32x4 hiN = *(const f32x4*)(emb + (size_t)tokG0 * DIM + eoff1);  \
        const bool  nzN = (tokG0 != 0);                                        \
        const int tokNew = xp[(TIDX)];                                         \
        const f32x4 acc1 = __builtin_amdgcn_mfma_f32_16x16x32_bf16(A1h, Bh.f, aePre1, 0, 0, 0); \
        const f32x4 acc0 = __builtin_amdgcn_mfma_f32_16x16x32_bf16(A0h, Bh.f, aePre0, 0, 0, 0); \
        I4B Be;                                                                \
        Be.i[0] = nzA ? cvt_pk_bf16(loA[0], loA[1]) : 0;                       \
        Be.i[1] = nzA ? cvt_pk_bf16(loA[2], loA[3]) : 0;                       \
        Be.i[2] = nzA ? cvt_pk_bf16(hiA[0], hiA[1]) : 0;                       \
        Be.i[3] = nzA ? cvt_pk_bf16(hiA[2], hiA[3]) : 0;                       \
        aePre0 = __builtin_amdgcn_mfma_f32_16x16x32_bf16(A0e, Be.f, zf, 0, 0, 0); \
        aePre1 = __builtin_amdgcn_mfma_f32_16x16x32_bf16(A1e, Be.f, zf, 0, 0, 0); \
        const v2f p2 = fast_tanh2_s((v2f){acc1[0], acc1[1]});                  \
        const v2f p3 = fast_tanh2_s((v2f){acc1[2], acc1[3]});                  \
        int tp0 = cvt_pk_bf16(p2.x, p2.y);                                     \
        int tp1 = cvt_pk_bf16(p3.x, p3.y);                                     \
        const v2f p0 = fast_tanh2_s((v2f){acc0[0], acc0[1]});                  \
        const v2f p1 = fast_tanh2_s((v2f){acc0[2], acc0[3]});                  \
        int w0 = cvt_pk_bf16(p0.x, p0.y);                                      \
        int w1 = cvt_pk_bf16(p1.x, p1.y);                                      \
        pl32swap(w0, tp0);   /* w'={w_lo,t_lo}; t'={w_hi,t_hi} */              \
        pl32swap(w1, tp1);                                                     \
        Bh.i[0] = w0; Bh.i[1] = w1; Bh.i[2] = tp0; Bh.i[3] = tp1;              \
        loA = loB; hiA = hiB; nzA = nzB;                                       \
        loB = loC; hiB = hiC; nzB = nzC;                                       \
        loC = loD; hiC = hiD; nzC = nzD;                                       \
        loD = loN; hiD = hiN; nzD = nzN;                                       \
        tokG0 = tokG1; tokG1 = tokG2; tokG2 = tokG3; tokG3 = tokNew;           \
    }

// One wave = 16 batch rows; plain loads; scheduler occupancy pinned to
// 1 wave/EU (r17-proven: keeps pipeline registers live, VGPR 48->132).
__global__ __launch_bounds__(256)
__attribute__((amdgpu_waves_per_eu(1, 1)))
void rnn_mfma(const int* __restrict__ x,
              const float* __restrict__ emb,
              const float* __restrict__ W_ih,
              const float* __restrict__ W_hh,
              const float* __restrict__ W_cls,
              const float* __restrict__ b_cls,
              float* __restrict__ out, int B)
{
    const int gtid = blockIdx.x * blockDim.x + threadIdx.x;
    const int wave = gtid >> 6;
    const int lane = (int)(threadIdx.x & 63);
    const int c = lane & 15;      // batch column of the tile
    const int q = lane >> 4;      // quadrant
    const int row0 = wave * 16;
    if (row0 >= B) return;

    // ---- A fragments: lane holds A[row=c][k=8q+j], zero outside bounds.
    // scale: recurrent matrices absorb ALPHA so MFMA output is exp2-ready.
    auto loadA = [&](const float* M, int U0, int ROWS, bool pk, float scale) {
        bf16x8 f;
        const int uu = U0 + c;
        const int ur = uu < ROWS ? uu : 0;
#pragma unroll
        for (int j = 0; j < 8; ++j) {
            const int kk = 8 * q + j;
            const int kp = pk ? permk(kk) : kk;
            const int kr = kp < DIM ? kp : 0;
            float v = M[ur * DIM + kr] * scale;
            v = (uu < ROWS && kk < DIM) ? v : 0.0f;
            __hip_bfloat16 hb = __float2bfloat16(v);
            f[j] = *reinterpret_cast<short*>(&hb);
        }
        return f;
    };
    const bf16x8 A0h = loadA(W_hh,  0, DIM,  true,  ALPHA);  // units 0-15,  W_hh
    const bf16x8 A0e = loadA(W_ih,  0, DIM,  false, ALPHA);  // units 0-15,  W_ih
    const bf16x8 A1h = loadA(W_hh, 16, DIM,  true,  ALPHA);  // units 16-19
    const bf16x8 A1e = loadA(W_ih, 16, DIM,  false, ALPHA);
    const bf16x8 Acl = loadA(W_cls, 0, NCLS, true,  1.0f);   // classes 0-4

    float bias[4];
#pragma unroll
    for (int j = 0; j < 4; ++j) {
        const int idx = 4 * q + j;
        bias[j] = (idx < NCLS) ? b_cls[idx] : 0.0f;
    }

    const int eoff0 = (q == 0) ? 0 : (q == 1) ? 8 : 16;   // e element offsets,
    const int eoff1 = (q == 0) ? 4 : (q == 1) ? 12 : 16;  // clamped in-bounds

    const int* xp = x + (size_t)(row0 + c) * SEQ;
    const f32x4 zf = {0.0f, 0.0f, 0.0f, 0.0f};

    // ---- prologue ----------------------------------------------------------
    I4B Bh; Bh.i[0] = Bh.i[1] = Bh.i[2] = Bh.i[3] = 0;
    const int tk0 = xp[0];
    const int tk1 = xp[1];
    const int tk2 = xp[2];
    const int tk3 = xp[3];
    const int tk4 = xp[4];
    f32x4 aePre0, aePre1;
    {   // e(0) -> aePre for step 0
        const f32x4 lo = *(const f32x4*)(emb + (size_t)tk0 * DIM + eoff0);
        const f32x4 hi = *(const f32x4*)(emb + (size_t)tk0 * DIM + eoff1);
        const bool nz = (tk0 != 0);    // padding_idx = 0
        I4B Be;
        Be.i[0] = nz ? cvt_pk_bf16(lo[0], lo[1]) : 0;
        Be.i[1] = nz ? cvt_pk_bf16(lo[2], lo[3]) : 0;
        Be.i[2] = nz ? cvt_pk_bf16(hi[0], hi[1]) : 0;
        Be.i[3] = nz ? cvt_pk_bf16(hi[2], hi[3]) : 0;
        aePre0 = __builtin_amdgcn_mfma_f32_16x16x32_bf16(A0e, Be.f, zf, 0, 0, 0);
        aePre1 = __builtin_amdgcn_mfma_f32_16x16x32_bf16(A1e, Be.f, zf, 0, 0, 0);
    }

    // stages A..D = e(1)..e(4); tokens x[5..8] in flight
    f32x4 loA, hiA, loB, hiB, loC, hiC, loD, hiD;
    bool nzA, nzB, nzC, nzD;
    loA = *(const f32x4*)(emb + (size_t)tk1 * DIM + eoff0);
    hiA = *(const f32x4*)(emb + (size_t)tk1 * DIM + eoff1);
    nzA = (tk1 != 0);
    loB = *(const f32x4*)(emb + (size_t)tk2 * DIM + eoff0);
    hiB = *(const f32x4*)(emb + (size_t)tk2 * DIM + eoff1);
    nzB = (tk2 != 0);
    loC = *(const f32x4*)(emb + (size_t)tk3 * DIM + eoff0);
    hiC = *(const f32x4*)(emb + (size_t)tk3 * DIM + eoff1);
    nzC = (tk3 != 0);
    loD = *(const f32x4*)(emb + (size_t)tk4 * DIM + eoff0);
    hiD = *(const f32x4*)(emb + (size_t)tk4 * DIM + eoff1);
    nzD = (tk4 != 0);
    int tokG0 = xp[5];
    int tokG1 = xp[6];
    int tokG2 = xp[7];
    int tokG3 = xp[8];

    // ---- main loop: no clamp needed while s+9 <= 255; 240 is 8-aligned -----
#pragma unroll 8
    for (int s = 0; s < 240; ++s) {
        STEP(s + 9)
    }
    // ---- tail: 16 steps with clamped token index ---------------------------
#pragma unroll 4
    for (int s = 240; s < SEQ; ++s) {
        STEP((s + 9 < SEQ) ? (s + 9) : (SEQ - 1))
    }

    // ---- classifier: one MFMA (classes in rows 0-4; k-cols >= 20 are zero)
    const f32x4 y = __builtin_amdgcn_mfma_f32_16x16x32_bf16(Acl, Bh.f, zf, 0, 0, 0);
    float* orow = out + (size_t)(row0 + c) * NCLS;
    if (q == 0) {          // rows 0-3 = classes 0-3 for batch row c
        orow[0] = y[0] + bias[0];
        orow[1] = y[1] + bias[1];
        orow[2] = y[2] + bias[2];
        orow[3] = y[3] + bias[3];
    } else if (q == 1) {   // row 4 = class 4
        orow[4] = y[0] + bias[0];
    }
}

extern "C" void kernel_launch(void* const* d_in, const int* in_sizes, int n_in,
                              void* d_out, int out_size, void* d_ws, size_t ws_size,
                              hipStream_t stream) {
    const int*   x     = (const int*)d_in[0];
    const float* emb   = (const float*)d_in[1];
    const float* W_ih  = (const float*)d_in[2];
    const float* W_hh  = (const float*)d_in[3];
    const float* W_cls = (const float*)d_in[4];
    const float* b_cls = (const float*)d_in[5];
    float* out = (float*)d_out;

    const int B = in_sizes[0] / SEQ;            // 16384
    const int threads = B * 4;                   // 64 lanes per 16 rows
    const int block = 256;
    const int grid = (threads + block - 1) / block;   // 1024 waves total
    rnn_mfma<<<grid, block, 0, stream>>>(x, emb, W_ih, W_hh, W_cls, b_cls, out, B);
}